// Round 3
// baseline (363.428 us; speedup 1.0000x reference)
//
#include <hip/hip_runtime.h>
#include <hip/hip_cooperative_groups.h>
#include <math.h>

namespace cg = cooperative_groups;

// Problem dims (fixed by setup_inputs): B=8, C=256, H=64, W=64, fp32.
#define BB 8
#define CC 256
#define HH 64
#define WW 64
#define EPS 1e-5f
#define GRID 512      // 2 blocks/CU on 256 CUs -> cooperative co-residency guaranteed
#define NTHR 256

struct Params {
    const float *x;
    const float *w_cw, *g_cw, *b_cw, *m_cw, *v_cw;
    const float *w_hc, *g_hc, *b_hc, *m_hc, *v_hc;
    const float *w_hw, *g_hw, *b_hw, *m_hw, *v_hw;
    const float *w1d;
    float *z1max, *z1mean, *z2max, *z2mean, *z3max, *z3mean;
    float *s1, *s2, *s3, *pooled, *out;
};

// 7x7 conv (2ch->1, zero pad) + inference BN + sigmoid for one output element.
__device__ __forceinline__ void conv_one(
    const float* __restrict__ zm, const float* __restrict__ za,
    const float* __restrict__ wp, const float* gp, const float* bp,
    const float* mp, const float* vp, float* __restrict__ sp,
    int R, int Cw, int o)
{
    int b   = o / (R * Cw);
    int rem = o - b * R * Cw;
    int r   = rem / Cw;
    int col = rem - r * Cw;
    const float* zmb = zm + (size_t)b * R * Cw;
    const float* zab = za + (size_t)b * R * Cw;
    float acc = 0.f;
    #pragma unroll
    for (int dr = 0; dr < 7; ++dr) {
        int rr = r + dr - 3;
        if (rr < 0 || rr >= R) continue;
        #pragma unroll
        for (int dc = 0; dc < 7; ++dc) {
            int cc2 = col + dc - 3;
            if (cc2 < 0 || cc2 >= Cw) continue;
            acc += wp[dr * 7 + dc]      * zmb[rr * Cw + cc2]
                 + wp[49 + dr * 7 + dc] * zab[rr * Cw + cc2];
        }
    }
    float scale = gp[0] * rsqrtf(vp[0] + EPS);
    float y = (acc - mp[0]) * scale + bp[0];
    sp[o] = 1.f / (1.f + __expf(-y));
}

__global__ __launch_bounds__(256, 2) void fused_kernel(Params p)
{
    __shared__ float smem[HH * 65 + 512];   // 18688 B; aliased per phase
    __shared__ float r4[4];
    cg::grid_group grid = cg::this_grid();
    int t   = threadIdx.x;
    int blk = blockIdx.x;
    int tid = blk * NTHR + t;

    float* tile = smem;            // [64][65]
    float* red  = smem + HH * 65;  // [512]

    // ================= Phase 1a: per-(b,c) pools (z1 over h, z2 over w) =====
    #pragma unroll 1
    for (int pidx = 0; pidx < 4; ++pidx) {
        int bc = blk + pidx * GRID;
        int b = bc >> 8, c = bc & 255;
        const float4* xt4 = (const float4*)p.x + (size_t)bc * 1024;
        __syncthreads();                       // protect LDS reuse
        #pragma unroll
        for (int i = 0; i < 4; ++i) {
            int idx = t + i * 256;
            float4 v = xt4[idx];
            int h = idx >> 4, w0 = (idx & 15) * 4;
            float* d = &tile[h * 65 + w0];
            d[0] = v.x; d[1] = v.y; d[2] = v.z; d[3] = v.w;
        }
        __syncthreads();
        {   // reduce over h (per w); t = hg*64 + w
            int w = t & 63, hg = t >> 6;
            float m = -INFINITY, s = 0.f;
            #pragma unroll
            for (int i = 0; i < 16; ++i) {
                float v = tile[(hg * 16 + i) * 65 + w];
                m = fmaxf(m, v); s += v;
            }
            red[t] = m; red[256 + t] = s;
        }
        __syncthreads();
        if (t < 64) {
            float m = red[t], s = red[256 + t];
            #pragma unroll
            for (int g = 1; g < 4; ++g) { m = fmaxf(m, red[g * 64 + t]); s += red[256 + g * 64 + t]; }
            p.z1max [bc * WW + t] = m;
            p.z1mean[bc * WW + t] = s * (1.f / 64.f);
        }
        __syncthreads();
        {   // reduce over w (per h); t = wg*64 + h
            int h = t & 63, wg = t >> 6;
            float m = -INFINITY, s = 0.f;
            #pragma unroll
            for (int i = 0; i < 16; ++i) {
                float v = tile[h * 65 + wg * 16 + i];
                m = fmaxf(m, v); s += v;
            }
            red[t] = m; red[256 + t] = s;
        }
        __syncthreads();
        if (t < 64) {
            float m = red[t], s = red[256 + t];
            #pragma unroll
            for (int g = 1; g < 4; ++g) { m = fmaxf(m, red[g * 64 + t]); s += red[256 + g * 64 + t]; }
            p.z2max [(b * HH + t) * CC + c] = m;
            p.z2mean[(b * HH + t) * CC + c] = s * (1.f / 64.f);
        }
    }

    // ================= Phase 1b: per-(b,h) pool over c (one unit per block) =
    {
        __syncthreads();
        int bh = blk;                  // exactly 512 units for 512 blocks
        int b = bh >> 6, h = bh & 63;
        int wq = t & 15, cgp = t >> 4; // 16 w-quads x 16 c-groups
        const float4* base = (const float4*)p.x
            + ((size_t)b * CC * HH * WW + (size_t)h * WW) / 4 + wq;
        float4 m = make_float4(-INFINITY, -INFINITY, -INFINITY, -INFINITY);
        float4 s = make_float4(0.f, 0.f, 0.f, 0.f);
        #pragma unroll 4
        for (int i = 0; i < 16; ++i) {
            float4 v = base[(size_t)(cgp * 16 + i) * 1024];   // c stride = H*W/4
            m.x = fmaxf(m.x, v.x); m.y = fmaxf(m.y, v.y);
            m.z = fmaxf(m.z, v.z); m.w = fmaxf(m.w, v.w);
            s.x += v.x; s.y += v.y; s.z += v.z; s.w += v.w;
        }
        float4* mred = (float4*)smem;
        float4* sred = (float4*)smem + 256;
        mred[t] = m; sred[t] = s;
        __syncthreads();
        if (t < 16) {
            float4 mm = mred[t], ss = sred[t];
            #pragma unroll
            for (int g = 1; g < 16; ++g) {
                float4 mv = mred[g * 16 + t], sv = sred[g * 16 + t];
                mm.x = fmaxf(mm.x, mv.x); mm.y = fmaxf(mm.y, mv.y);
                mm.z = fmaxf(mm.z, mv.z); mm.w = fmaxf(mm.w, mv.w);
                ss.x += sv.x; ss.y += sv.y; ss.z += sv.z; ss.w += sv.w;
            }
            ss.x *= (1.f / 256.f); ss.y *= (1.f / 256.f);
            ss.z *= (1.f / 256.f); ss.w *= (1.f / 256.f);
            *(float4*)(p.z3max  + bh * WW + t * 4) = mm;
            *(float4*)(p.z3mean + bh * WW + t * 4) = ss;
        }
    }

    grid.sync();

    // ================= Phase 2: conv + BN + sigmoid gates ===================
    #pragma unroll 1
    for (int o = tid; o < 294912; o += GRID * NTHR) {
        if (o < 131072)
            conv_one(p.z1max, p.z1mean, p.w_cw, p.g_cw, p.b_cw, p.m_cw, p.v_cw, p.s1, CC, WW, o);
        else if (o < 262144)
            conv_one(p.z2max, p.z2mean, p.w_hc, p.g_hc, p.b_hc, p.m_hc, p.v_hc, p.s2, HH, CC, o - 131072);
        else
            conv_one(p.z3max, p.z3mean, p.w_hw, p.g_hw, p.b_hw, p.m_hw, p.v_hw, p.s3, HH, WW, o - 262144);
    }

    grid.sync();

    // ================= Phase 3: pooled[b,c] =================================
    // pooled = (Σ_{h,w} x*s3 + 64*Σ_w s1*z1mean + 64*Σ_h s2*z2mean) / 12288
    #pragma unroll 1
    for (int pidx = 0; pidx < 4; ++pidx) {
        int bc = blk + pidx * GRID;
        int b = bc >> 8, c = bc & 255;
        const float4* xt4 = (const float4*)p.x  + (size_t)bc * 1024;
        const float4* s34 = (const float4*)p.s3 + (size_t)b * 1024;
        float acc = 0.f;
        #pragma unroll
        for (int i = 0; i < 4; ++i) {
            float4 xv = xt4[t + i * 256];
            float4 sv = s34[t + i * 256];
            acc += xv.x * sv.x + xv.y * sv.y + xv.z * sv.z + xv.w * sv.w;
        }
        if (t < 64) {
            acc += 64.f * p.s1[bc * WW + t] * p.z1mean[bc * WW + t];
        } else if (t < 128) {
            int idx = (b * HH + (t - 64)) * CC + c;
            acc += 64.f * p.s2[idx] * p.z2mean[idx];
        }
        #pragma unroll
        for (int off = 32; off >= 1; off >>= 1) acc += __shfl_down(acc, off);
        if ((t & 63) == 0) r4[t >> 6] = acc;
        __syncthreads();
        if (t == 0) p.pooled[bc] = (r4[0] + r4[1] + r4[2] + r4[3]) * (1.f / (4096.f * 3.f));
        __syncthreads();
    }

    grid.sync();

    // ================= Phase 4: out = x * Σ_k wts_k * s_k ===================
    #pragma unroll 1
    for (int j = 0; j < 16; ++j) {
        int i4 = j * (GRID * NTHR) + tid;       // coalesced float4 index
        int w0   = (i4 & 15) * 4;
        int rest = i4 >> 4;
        int h = rest & 63; rest >>= 6;
        int c = rest & 255;
        int b = rest >> 8;

        float lg0 = 0.f, lg1 = 0.f, lg2 = 0.f;
        #pragma unroll
        for (int jj = 0; jj < 7; ++jj) {
            int cc2 = c + jj - 3;
            float pv = (cc2 >= 0 && cc2 < CC) ? p.pooled[b * CC + cc2] : 0.f;
            lg0 += p.w1d[jj] * pv;
            lg1 += p.w1d[7 + jj] * pv;
            lg2 += p.w1d[14 + jj] * pv;
        }
        float mx = fmaxf(lg0, fmaxf(lg1, lg2));
        float e0 = __expf(lg0 - mx), e1 = __expf(lg1 - mx), e2 = __expf(lg2 - mx);
        float inv = 1.f / (e0 + e1 + e2);
        float k0 = e0 * inv, k1 = e1 * inv, k2 = e2 * inv;

        const float4 x4  = *(const float4*)(p.x  + (size_t)i4 * 4);
        const float4 s1v = *(const float4*)(p.s1 + ((size_t)(b * CC + c)) * WW + w0);
        const float  s2v = p.s2[(b * HH + h) * CC + c];
        const float4 s3v = *(const float4*)(p.s3 + ((size_t)(b * HH + h)) * WW + w0);

        float4 o;
        o.x = x4.x * (k0 * s1v.x + k1 * s2v + k2 * s3v.x);
        o.y = x4.y * (k0 * s1v.y + k1 * s2v + k2 * s3v.y);
        o.z = x4.z * (k0 * s1v.z + k1 * s2v + k2 * s3v.z);
        o.w = x4.w * (k0 * s1v.w + k1 * s2v + k2 * s3v.w);
        *(float4*)(p.out + (size_t)i4 * 4) = o;
    }
}

// ---------------------------------------------------------------------------
extern "C" void kernel_launch(void* const* d_in, const int* in_sizes, int n_in,
                              void* d_out, int out_size, void* d_ws, size_t ws_size,
                              hipStream_t stream)
{
    Params pp;
    pp.x    = (const float*)d_in[0];
    pp.w_cw = (const float*)d_in[1];
    pp.g_cw = (const float*)d_in[2];
    pp.b_cw = (const float*)d_in[3];
    pp.m_cw = (const float*)d_in[4];
    pp.v_cw = (const float*)d_in[5];
    pp.w_hc = (const float*)d_in[6];
    pp.g_hc = (const float*)d_in[7];
    pp.b_hc = (const float*)d_in[8];
    pp.m_hc = (const float*)d_in[9];
    pp.v_hc = (const float*)d_in[10];
    pp.w_hw = (const float*)d_in[11];
    pp.g_hw = (const float*)d_in[12];
    pp.b_hw = (const float*)d_in[13];
    pp.m_hw = (const float*)d_in[14];
    pp.v_hw = (const float*)d_in[15];
    pp.w1d  = (const float*)d_in[16];
    pp.out  = (float*)d_out;

    float* ws = (float*)d_ws;
    const size_t N1 = (size_t)BB * CC * WW;   // 131072  [B,C,W]
    const size_t N2 = (size_t)BB * HH * CC;   // 131072  [B,H,C]
    const size_t N3 = (size_t)BB * HH * WW;   // 32768   [B,H,W]
    pp.z1max  = ws;
    pp.z1mean = pp.z1max  + N1;
    pp.z2max  = pp.z1mean + N1;
    pp.z2mean = pp.z2max  + N2;
    pp.z3max  = pp.z2mean + N2;
    pp.z3mean = pp.z3max  + N3;
    pp.s1     = pp.z3mean + N3;
    pp.s2     = pp.s1 + N1;
    pp.s3     = pp.s2 + N2;
    pp.pooled = pp.s3 + N3;                   // B*C = 2048

    void* args[] = { &pp };
    hipLaunchCooperativeKernel((const void*)fused_kernel, dim3(GRID), dim3(NTHR),
                               args, 0, stream);
}

// Round 4
// 147.208 us; speedup vs baseline: 2.4688x; 2.4688x over previous
//
#include <hip/hip_runtime.h>
#include <math.h>

// Problem dims (fixed by setup_inputs): B=8, C=256, H=64, W=64, fp32.
#define BB 8
#define CC 256
#define HH 64
#define WW 64
#define EPS 1e-5f
#define PSCALE (1.f / 12288.f)   // 1/(H*W*3)

// ---------------------------------------------------------------------------
// K1: fused pooling, one x pass.  Also zero-inits pooled[2048] (blocks 0..7).
//   blocks [0,2048):   bc-planes -> z1 (over h), z2 (over w)
//   blocks [2048,2560): bh units  -> z3 (over c)
// ---------------------------------------------------------------------------
__global__ __launch_bounds__(256) void pool_kernel(
    const float* __restrict__ x,
    float* __restrict__ z1max, float* __restrict__ z1mean,
    float* __restrict__ z2max, float* __restrict__ z2mean,
    float* __restrict__ z3max, float* __restrict__ z3mean,
    float* __restrict__ pooled)
{
    __shared__ float smem[HH * 65 + 512];
    int blk = blockIdx.x;
    int t = threadIdx.x;

    if (blk < 8) pooled[blk * 256 + t] = 0.f;   // zero 2048 accumulators

    if (blk < BB * CC) {
        int bc = blk;
        int b = bc >> 8, c = bc & 255;
        const float4* xt4 = (const float4*)x + (size_t)bc * 1024;
        float* tile = smem;                    // [64][65]
        float* red  = smem + HH * 65;          // [512]

        #pragma unroll
        for (int i = 0; i < 4; ++i) {
            int idx = t + i * 256;
            float4 v = xt4[idx];
            int h = idx >> 4, w0 = (idx & 15) * 4;
            float* d = &tile[h * 65 + w0];
            d[0] = v.x; d[1] = v.y; d[2] = v.z; d[3] = v.w;
        }
        __syncthreads();

        {   // reduce over h (per w); t = hg*64 + w
            int w = t & 63, hg = t >> 6;
            float m = -INFINITY, s = 0.f;
            #pragma unroll
            for (int i = 0; i < 16; ++i) {
                float v = tile[(hg * 16 + i) * 65 + w];
                m = fmaxf(m, v); s += v;
            }
            red[t] = m; red[256 + t] = s;
        }
        __syncthreads();
        if (t < 64) {
            float m = red[t], s = red[256 + t];
            #pragma unroll
            for (int g = 1; g < 4; ++g) { m = fmaxf(m, red[g * 64 + t]); s += red[256 + g * 64 + t]; }
            z1max [bc * WW + t] = m;
            z1mean[bc * WW + t] = s * (1.f / 64.f);
        }
        __syncthreads();

        {   // reduce over w (per h); t = wg*64 + h
            int h = t & 63, wg = t >> 6;
            float m = -INFINITY, s = 0.f;
            #pragma unroll
            for (int i = 0; i < 16; ++i) {
                float v = tile[h * 65 + wg * 16 + i];
                m = fmaxf(m, v); s += v;
            }
            red[t] = m; red[256 + t] = s;
        }
        __syncthreads();
        if (t < 64) {
            float m = red[t], s = red[256 + t];
            #pragma unroll
            for (int g = 1; g < 4; ++g) { m = fmaxf(m, red[g * 64 + t]); s += red[256 + g * 64 + t]; }
            z2max [(b * HH + t) * CC + c] = m;
            z2mean[(b * HH + t) * CC + c] = s * (1.f / 64.f);
        }
    } else {
        int bh = blk - BB * CC;
        int b = bh >> 6, h = bh & 63;
        int wq = t & 15, cgp = t >> 4;         // 16 w-quads x 16 c-groups

        const float4* base = (const float4*)x
            + ((size_t)b * CC * HH * WW + (size_t)h * WW) / 4 + wq;
        float4 m = make_float4(-INFINITY, -INFINITY, -INFINITY, -INFINITY);
        float4 s = make_float4(0.f, 0.f, 0.f, 0.f);
        #pragma unroll 4
        for (int i = 0; i < 16; ++i) {
            float4 v = base[(size_t)(cgp * 16 + i) * 1024];
            m.x = fmaxf(m.x, v.x); m.y = fmaxf(m.y, v.y);
            m.z = fmaxf(m.z, v.z); m.w = fmaxf(m.w, v.w);
            s.x += v.x; s.y += v.y; s.z += v.z; s.w += v.w;
        }
        float4* mred = (float4*)smem;
        float4* sred = (float4*)smem + 256;
        mred[t] = m; sred[t] = s;
        __syncthreads();
        if (t < 16) {
            float4 mm = mred[t], ss = sred[t];
            #pragma unroll
            for (int g = 1; g < 16; ++g) {
                float4 mv = mred[g * 16 + t], sv = sred[g * 16 + t];
                mm.x = fmaxf(mm.x, mv.x); mm.y = fmaxf(mm.y, mv.y);
                mm.z = fmaxf(mm.z, mv.z); mm.w = fmaxf(mm.w, mv.w);
                ss.x += sv.x; ss.y += sv.y; ss.z += sv.z; ss.w += sv.w;
            }
            ss.x *= (1.f / 256.f); ss.y *= (1.f / 256.f);
            ss.z *= (1.f / 256.f); ss.w *= (1.f / 256.f);
            *(float4*)(z3max  + bh * WW + t * 4) = mm;
            *(float4*)(z3mean + bh * WW + t * 4) = ss;
        }
    }
}

// 7x7 conv (2ch->1, zero pad) + inference BN + sigmoid -> gate value.
__device__ __forceinline__ float conv_gate(
    const float* __restrict__ zm, const float* __restrict__ za,
    const float* __restrict__ wp, const float* gp, const float* bp,
    const float* mp, const float* vp,
    int R, int Cw, int b, int r, int col)
{
    const float* zmb = zm + (size_t)b * R * Cw;
    const float* zab = za + (size_t)b * R * Cw;
    float acc = 0.f;
    #pragma unroll
    for (int dr = 0; dr < 7; ++dr) {
        int rr = r + dr - 3;
        if (rr < 0 || rr >= R) continue;
        #pragma unroll
        for (int dc = 0; dc < 7; ++dc) {
            int cc2 = col + dc - 3;
            if (cc2 < 0 || cc2 >= Cw) continue;
            acc += wp[dr * 7 + dc]      * zmb[rr * Cw + cc2]
                 + wp[49 + dr * 7 + dc] * zab[rr * Cw + cc2];
        }
    }
    float scale = gp[0] * rsqrtf(vp[0] + EPS);
    float y = (acc - mp[0]) * scale + bp[0];
    return 1.f / (1.f + __expf(-y));
}

// ---------------------------------------------------------------------------
// K2: gates for all 3 branches + pooled accumulation (raw sums, atomics).
//   raw[b,c] = 64*Σ_w s1*z1mean + 64*Σ_h s2*z2mean + Σ_{h,w} x*s3
//   blocks [0,512):     branch 0 (s1, [C,W])  — wave-reduced atomic per (b,c)
//   blocks [512,1024):  branch 1 (s2, [H,C])  — per-thread atomic
//   blocks [1024,1536): branch 2 (s3, [H,W])  — s3 row + x·s3 pass, 4-lane reduce
// ---------------------------------------------------------------------------
__global__ __launch_bounds__(256) void gate_kernel(
    const float* __restrict__ x,
    const float* __restrict__ z1max, const float* __restrict__ z1mean,
    const float* __restrict__ w0p, const float* g0, const float* b0,
    const float* m0, const float* v0, float* __restrict__ s1,
    const float* __restrict__ z2max, const float* __restrict__ z2mean,
    const float* __restrict__ w1p, const float* g1, const float* b1,
    const float* m1, const float* v1, float* __restrict__ s2,
    const float* __restrict__ z3max, const float* __restrict__ z3mean,
    const float* __restrict__ w2p, const float* g2, const float* b2,
    const float* m2, const float* v2, float* __restrict__ s3,
    float* __restrict__ pooled)
{
    int blk = blockIdx.x;
    int t = threadIdx.x;

    if (blk < 512) {
        // ---- branch 0: o over [B,C,W]; a wave = one (b,c) row of 64 w ----
        int o = blk * 256 + t;
        int b = o >> 14, rem = o & 16383;
        int r = rem >> 6, col = o & 63;
        float v = conv_gate(z1max, z1mean, w0p, g0, b0, m0, v0, CC, WW, b, r, col);
        s1[o] = v;
        float prod = v * z1mean[o];
        #pragma unroll
        for (int off = 32; off >= 1; off >>= 1) prod += __shfl_down(prod, off);
        if ((t & 63) == 0) atomicAdd(&pooled[o >> 6], 64.f * prod);
    } else if (blk < 1024) {
        // ---- branch 1: o over [B,H,C] ----
        int o = (blk - 512) * 256 + t;
        int b = o >> 14, rem = o & 16383;
        int r = rem >> 8, col = o & 255;       // r=h, col=c
        float v = conv_gate(z2max, z2mean, w1p, g1, b1, m1, v1, HH, CC, b, r, col);
        s2[o] = v;
        atomicAdd(&pooled[(b << 8) | col], 64.f * v * z2mean[o]);
    } else {
        // ---- branch 2: one block per (b,h) ----
        __shared__ float s3row[WW];
        int bh = blk - 1024;
        int b = bh >> 6, h = bh & 63;
        if (t < 64) {
            float v = conv_gate(z3max, z3mean, w2p, g2, b2, m2, v2, HH, WW, b, h, t);
            s3[bh * WW + t] = v;
            s3row[t] = v;
        }
        __syncthreads();

        // x·s3 over all 256 c for this (b,h).  Lane layout within a wave:
        //   l = c_local*4 + wsub : 16 c's x 4 w-chunks of 16.
        int wv = t >> 6, l = t & 63;
        int c_local = l >> 2, wsub = l & 3;
        const float4* s3q4 = (const float4*)s3row;    // 16 quads

        #pragma unroll 1
        for (int pass = 0; pass < 4; ++pass) {
            int c = pass * 64 + (wv << 4) + c_local;
            const float4* xr4 = (const float4*)x
                + ((size_t)(b * 256 + c) * 4096 + h * 64) / 4 + wsub * 4;
            float acc = 0.f;
            #pragma unroll
            for (int j = 0; j < 4; ++j) {
                float4 xv = xr4[j];
                float4 sv = s3q4[wsub * 4 + j];
                acc += xv.x * sv.x + xv.y * sv.y + xv.z * sv.z + xv.w * sv.w;
            }
            acc += __shfl_xor(acc, 1);
            acc += __shfl_xor(acc, 2);
            if (wsub == 0) atomicAdd(&pooled[b * 256 + c], acc);
        }
    }
}

// ---------------------------------------------------------------------------
// K3: out = x * (k0*s1[b,c,w] + k1*s2[b,h,c] + k2*s3[b,h,w])
//     softmax weights from raw pooled sums (scale folded into logits).
// ---------------------------------------------------------------------------
__global__ __launch_bounds__(256) void final_kernel(
    const float* __restrict__ x,
    const float* __restrict__ s1, const float* __restrict__ s2,
    const float* __restrict__ s3, const float* __restrict__ pooled,
    const float* __restrict__ w1d, float* __restrict__ out)
{
    int i4 = blockIdx.x * 256 + threadIdx.x;      // float4 index
    int w0   = (i4 & 15) * 4;
    int rest = i4 >> 4;
    int h = rest & 63; rest >>= 6;
    int c = rest & 255;
    int b = rest >> 8;

    float lg0 = 0.f, lg1 = 0.f, lg2 = 0.f;
    #pragma unroll
    for (int jj = 0; jj < 7; ++jj) {
        int cc2 = c + jj - 3;
        float pv = (cc2 >= 0 && cc2 < CC) ? pooled[b * CC + cc2] : 0.f;
        lg0 += w1d[jj] * pv;
        lg1 += w1d[7 + jj] * pv;
        lg2 += w1d[14 + jj] * pv;
    }
    lg0 *= PSCALE; lg1 *= PSCALE; lg2 *= PSCALE;
    float mx = fmaxf(lg0, fmaxf(lg1, lg2));
    float e0 = __expf(lg0 - mx), e1 = __expf(lg1 - mx), e2 = __expf(lg2 - mx);
    float inv = 1.f / (e0 + e1 + e2);
    float k0 = e0 * inv, k1 = e1 * inv, k2 = e2 * inv;

    const float4 x4  = *(const float4*)(x  + (size_t)i4 * 4);
    const float4 s1v = *(const float4*)(s1 + ((size_t)(b * CC + c)) * WW + w0);
    const float  s2v = s2[(b * HH + h) * CC + c];
    const float4 s3v = *(const float4*)(s3 + ((size_t)(b * HH + h)) * WW + w0);

    float4 o;
    o.x = x4.x * (k0 * s1v.x + k1 * s2v + k2 * s3v.x);
    o.y = x4.y * (k0 * s1v.y + k1 * s2v + k2 * s3v.y);
    o.z = x4.z * (k0 * s1v.z + k1 * s2v + k2 * s3v.z);
    o.w = x4.w * (k0 * s1v.w + k1 * s2v + k2 * s3v.w);
    *(float4*)(out + (size_t)i4 * 4) = o;
}

// ---------------------------------------------------------------------------
extern "C" void kernel_launch(void* const* d_in, const int* in_sizes, int n_in,
                              void* d_out, int out_size, void* d_ws, size_t ws_size,
                              hipStream_t stream)
{
    const float* x    = (const float*)d_in[0];
    const float* w_cw = (const float*)d_in[1];
    const float* g_cw = (const float*)d_in[2];
    const float* b_cw = (const float*)d_in[3];
    const float* m_cw = (const float*)d_in[4];
    const float* v_cw = (const float*)d_in[5];
    const float* w_hc = (const float*)d_in[6];
    const float* g_hc = (const float*)d_in[7];
    const float* b_hc = (const float*)d_in[8];
    const float* m_hc = (const float*)d_in[9];
    const float* v_hc = (const float*)d_in[10];
    const float* w_hw = (const float*)d_in[11];
    const float* g_hw = (const float*)d_in[12];
    const float* b_hw = (const float*)d_in[13];
    const float* m_hw = (const float*)d_in[14];
    const float* v_hw = (const float*)d_in[15];
    const float* w1d  = (const float*)d_in[16];
    float* out = (float*)d_out;

    float* ws = (float*)d_ws;
    const size_t N1 = (size_t)BB * CC * WW;   // 131072  [B,C,W]
    const size_t N2 = (size_t)BB * HH * CC;   // 131072  [B,H,C]
    const size_t N3 = (size_t)BB * HH * WW;   // 32768   [B,H,W]
    float* z1max  = ws;
    float* z1mean = z1max  + N1;
    float* z2max  = z1mean + N1;
    float* z2mean = z2max  + N2;
    float* z3max  = z2mean + N2;
    float* z3mean = z3max  + N3;
    float* s1     = z3mean + N3;
    float* s2     = s1 + N1;
    float* s3     = s2 + N2;
    float* pooled = s3 + N3;                  // B*C = 2048 raw sums

    pool_kernel<<<BB * CC + BB * HH, 256, 0, stream>>>(
        x, z1max, z1mean, z2max, z2mean, z3max, z3mean, pooled);

    gate_kernel<<<1536, 256, 0, stream>>>(
        x,
        z1max, z1mean, w_cw, g_cw, b_cw, m_cw, v_cw, s1,
        z2max, z2mean, w_hc, g_hc, b_hc, m_hc, v_hc, s2,
        z3max, z3mean, w_hw, g_hw, b_hw, m_hw, v_hw, s3,
        pooled);

    final_kernel<<<(BB * CC * HH * WW / 4) / 256, 256, 0, stream>>>(
        x, s1, s2, s3, pooled, w1d, out);
}